// Round 2
// baseline (784.368 us; speedup 1.0000x reference)
//
#include <hip/hip_runtime.h>

// Problem constants (from setup_inputs): E=8192, L=60, C=48, fp32.
#define NE   8192
#define NL   60
#define NC   48
#define NLM1 (NL - 1)                 // 59
#define NCOL (NE * NC)                // 393216 columns
#define OUT_PLANE (NE * NLM1 * NC)    // 23,199,744 per output tensor

// Fast reciprocal: v_rcp_f32 + one Newton step (~0.5 ulp). Operands are
// 1 +/- tmp with |tmp| < ~0.25 — well-conditioned.
__device__ __forceinline__ float rcp_nr(float x) {
    float y = __builtin_amdgcn_rcpf(x);
    return y * (2.0f - x * y);
}

// One thread per (e,c) column. Two fused passes.
//
// Register-pressure redesign vs the 532.6us version: stash ONLY rs_below[l]
// (59 regs) instead of add/tm/h (177 regs). Pass B re-reads r,t,s
// (L2/L3-temporal within the block's lifetime) and recomputes add/tm/h
// with the IDENTICAL op sequence as before, so numerics are unchanged.
// Target: <=128 VGPRs -> 16 waves/CU tier (was ~8 at the 256-VGPR tier).
__global__ __launch_bounds__(256, 4)
void adding_doubling_kernel(const float* __restrict__ a,
                            const float* __restrict__ r,
                            const float* __restrict__ t,
                            const float* __restrict__ s,
                            float* __restrict__ out) {
    int tid = blockIdx.x * blockDim.x + threadIdx.x;
    if (tid >= NCOL) return;
    int e = tid / NC;
    int c = tid - e * NC;
    int base_in  = e * (NL * NC) + c;    // + l*NC for layer l
    int base_out = e * (NLM1 * NC) + c;  // + l*NC for layer l

    float* __restrict__ fu_out = out;                  // flux_up
    float* __restrict__ fd_out = out + OUT_PLANE;      // flux_down
    float* __restrict__ ab_out = out + 2 * OUT_PLANE;  // absorbed

    // Per-layer stash: rs_below[l] = rs_body[l+1] (one float per layer).
    float rsb_v[NLM1];

    // ---- Pass A: backward over l = 58..0 (rs recursion + flux_up scan) ----
    {
        float r59 = r[base_in + 59 * NC];
        float t59 = t[base_in + 59 * NC];
        float s59 = s[base_in + 59 * NC];
        float carry_rs = fmaf(r59 * t59, t59, r59) * rcp_nr(1.0f - r59 * r59);
        float s_hi = s59;
        float fu_carry = 0.0f;

        #pragma unroll
        for (int l = NLM1 - 1; l >= 0; --l) {
            float rl = r[base_in + l * NC];
            float tl = t[base_in + l * NC];
            float sl = s[base_in + l * NC];
            float rsb   = carry_rs;            // rs_below[l] = rs_body[l+1]
            rsb_v[l] = rsb;
            float tmp   = rsb * rl;
            float inv_d = rcp_nr(1.0f - tmp);  // 1/d[l]
            float inv_p = rcp_nr(1.0f + tmp);
            // flux_up step: flux = carry + s_multi_up + s_multi_down_up
            float su   = s_hi * fmaf(tmp, inv_p, 1.0f); // s[l+1]*(1 + tmp/(1+tmp))
            float sd   = sl * rsb * inv_p;              // s[l]*rs_below/(1+tmp)
            float flux = fu_carry + su + sd;
            fu_out[base_out + l * NC] = flux;
            fu_carry = flux * tl * inv_d;               // flux * t / d
            // rs recursion: rs_body[l] = (r + rs_below*t^2)/(1 - tmp)
            carry_rs = fmaf(rsb * tl, tl, rl) * inv_d;
            s_hi = sl;
        }
    }

    // ---- Pass B: forward over l = 0..58; recompute add/tm/h from
    //      re-read r,t,s (cache-hot) + stashed rs_below ----
    {
        float flux = 0.0f;
        float sl = s[base_in];                 // s[l] rolling register
        #pragma unroll
        for (int l = 0; l < NLM1; ++l) {
            float rl   = r[base_in + l * NC];
            float tl   = t[base_in + l * NC];
            float s_hi = s[base_in + (l + 1) * NC];
            float al   = a[base_in + l * NC];
            float ful  = fu_out[base_out + l * NC];  // written in pass A; L2-hot
            float rsb  = rsb_v[l];
            float tmp   = rsb * rl;
            float inv_d = rcp_nr(1.0f - tmp);
            float inv_p = rcp_nr(1.0f + tmp);
            float add = fmaf(s_hi, rl, sl) * inv_d;   // s_multi_down + s_multi_up_down
            float tm  = tl * inv_p;                   // t_multi
            float h   = fmaf(tl * rsb, inv_p, 1.0f);  // a_multi = a*h
            flux += add;
            fd_out[base_out + l * NC] = flux;
            ab_out[base_out + l * NC] = al * fmaf(h, flux, ful);
            flux *= tm;
            sl = s_hi;
        }
    }
}

extern "C" void kernel_launch(void* const* d_in, const int* in_sizes, int n_in,
                              void* d_out, int out_size, void* d_ws, size_t ws_size,
                              hipStream_t stream) {
    const float* a = (const float*)d_in[0];
    const float* r = (const float*)d_in[1];
    const float* t = (const float*)d_in[2];
    const float* s = (const float*)d_in[3];
    float* out = (float*)d_out;

    dim3 block(256);
    dim3 grid((NCOL + 255) / 256);  // 1536 blocks
    adding_doubling_kernel<<<grid, block, 0, stream>>>(a, r, t, s, out);
}